// Round 5
// baseline (15916.096 us; speedup 1.0000x reference)
//
#include <hip/hip_runtime.h>

typedef _Float16 half2_t __attribute__((ext_vector_type(2)));
typedef unsigned uint_t;

#define B_    32
#define TE_   256
#define TD_   256
#define ENC_  512
#define HID_  1024
#define ATT_  128
#define OUT_  80
#define PRE_  256

// output regions (floats)
#define LOG_OFF  655360u
#define ATTW_OFF 663552u

// workspace offsets (float units)
#define OFF_PM    0u          // [32][128][256] f32 (transposed pm)
#define OFF_P1H   1048576u    // [256][32][128] uint (fp16x2 prenet out)
#define OFF_M     2097152u    // [128*31] f32
#define OFF_WWHT  2101248u    // [512][128] uint (fp16x2 Ww TRANSPOSED: [kpair][arow])
#define OFF_ENCH  2166784u    // [32][256][256] uint (fp16x2 enc)
#define OFF_W0P   4263936u    // [4096][896] uint (fp16x2 lstm0 w)
#define OFF_W1P   7933952u    // [4096][1024] uint (fp16x2 lstm1 w)
#define OFF_XC0   12128256u   // [32][1408] uint: [ac 256|p1 128|h0_e 512|h0_o 512]
#define OFF_XC1   12173312u   // [32][1024] uint: [h1_e 512|h1_o 512]
#define OFF_C0    12206080u   // [1024][32] f32
#define OFF_C1    12238848u   // [1024][32] f32
#define OFF_CUM   12271616u   // [32][256] f32
#define OFF_ATTC  12279808u   // [3][32][512] f32 ring
#define OFF_END   12328960u

__device__ __forceinline__ float rcp_f(float x){ return __builtin_amdgcn_rcpf(x); }
__device__ __forceinline__ float sigm(float x){ return rcp_f(1.0f + __expf(-x)); }
__device__ __forceinline__ float tanh_f(float x){ float e = __expf(2.0f*x); return 1.0f - 2.0f*rcp_f(e+1.0f); }

__device__ __forceinline__ uint_t packh2(float a, float b){
  half2_t h; h[0] = (_Float16)a; h[1] = (_Float16)b;
  return __builtin_bit_cast(uint_t, h);
}
__device__ __forceinline__ float dot2f(uint_t w, uint_t x, float c){
#if __has_builtin(__builtin_amdgcn_fdot2)
  return __builtin_amdgcn_fdot2(__builtin_bit_cast(half2_t, w),
                                __builtin_bit_cast(half2_t, x), c, false);
#else
  half2_t a = __builtin_bit_cast(half2_t, w), b = __builtin_bit_cast(half2_t, x);
  return c + (float)a[0]*(float)b[0] + (float)a[1]*(float)b[1];
#endif
}

// ---------------- one-time kernels ----------------

__global__ void k_init(float* __restrict__ ws){
  unsigned n = OFF_END - OFF_XC0;
  for (unsigned i = blockIdx.x*blockDim.x + threadIdx.x; i < n; i += gridDim.x*blockDim.x)
    ws[OFF_XC0 + i] = 0.f;
}

__global__ void k_precm(const float* __restrict__ Uw, const float* __restrict__ Fw,
                        float* __restrict__ ws){
  float* M = ws + OFF_M;
  for (int idx = threadIdx.x; idx < 128*31; idx += blockDim.x){
    int a = idx / 31, k = idx % 31;
    float s = 0.f;
    for (int c = 0; c < 32; c++) s += Uw[a*32+c]*Fw[c*31+k];
    M[idx] = s;
  }
}

// Ww transposed to [kpair][arow] for coalesced Wh GEMV
__global__ void k_cvtww(const float* __restrict__ Ww, float* __restrict__ ws){
  uint_t* WT = (uint_t*)(ws + OFF_WWHT);
  int p = blockIdx.x;                       // 0..511
  for (int a = threadIdx.x; a < 128; a += blockDim.x)
    WT[p*128 + a] = packh2(Ww[a*1024 + 2*p], Ww[a*1024 + 2*p + 1]);
}

__global__ void k_packenc(const float* __restrict__ enc, float* __restrict__ ws){
  uint_t* ENCH = (uint_t*)(ws + OFF_ENCH);
  size_t row = blockIdx.x;           // b*256 + p, 8192 rows
  for (int j = threadIdx.x; j < 256; j += blockDim.x)
    ENCH[row*256 + j] = packh2(enc[row*512 + 2*j], enc[row*512 + 2*j + 1]);
}

__global__ void k_packw0(const float* __restrict__ wih, const float* __restrict__ whh,
                         float* __restrict__ ws){
  uint_t* W = (uint_t*)(ws + OFF_W0P);
  size_t r = blockIdx.x;             // 4096 rows
  for (int p = threadIdx.x; p < 896; p += blockDim.x){
    int k = 2*p;
    const float* src = (k < 768) ? (wih + r*768 + k) : (whh + r*1024 + (k-768));
    W[r*896 + p] = packh2(src[0], src[1]);
  }
}

__global__ void k_packw1(const float* __restrict__ wih, const float* __restrict__ whh,
                         float* __restrict__ ws){
  uint_t* W = (uint_t*)(ws + OFF_W1P);
  size_t r = blockIdx.x;
  for (int p = threadIdx.x; p < 1024; p += blockDim.x){
    int k = 2*p;
    const float* src = (k < 1024) ? (wih + r*1024 + k) : (whh + r*1024 + (k-1024));
    W[r*1024 + p] = packh2(src[0], src[1]);
  }
}

// processed_memory TRANSPOSED: pm[b][a][s]
__global__ __launch_bounds__(256) void k_pm(const float* __restrict__ enc,
    const float* __restrict__ Vw, const float* __restrict__ Vb, float* __restrict__ ws){
  float* pm = ws + OFF_PM;
  int b  = blockIdx.x >> 2;
  int s0 = (blockIdx.x & 3) << 6;
  int a  = threadIdx.x & 127;
  int sh = threadIdx.x >> 7;
  __shared__ float Vl[128*65];
  __shared__ float El[64*64];
  float acc[32];
  #pragma unroll
  for (int i=0;i<32;i++) acc[i]=0.f;
  for (int kc=0; kc<ENC_; kc+=64){
    for (int i=threadIdx.x; i<128*64; i+=256){
      int aa = i>>6, kk = i&63;
      Vl[aa*65+kk] = Vw[aa*ENC_ + kc + kk];
    }
    for (int i=threadIdx.x; i<64*64; i+=256){
      int ss = i>>6, kk = i&63;
      El[i] = enc[(size_t)(b*TE_ + s0 + ss)*ENC_ + kc + kk];
    }
    __syncthreads();
    for (int k=0;k<64;k++){
      float va = Vl[a*65+k];
      const float* er = &El[(sh*32)*64 + k];
      #pragma unroll
      for (int s=0;s<32;s++) acc[s] += va * er[s*64];
    }
    __syncthreads();
  }
  float bb = Vb[a];
  for (int s=0;s<32;s++)
    pm[((size_t)b*128 + a)*256 + (s0 + sh*32 + s)] = acc[s] + bb;
}

// fused prenet (both layers), writes P1H fp16 pairs
__global__ __launch_bounds__(256) void k_pre(const float* __restrict__ tgt,
    const float* __restrict__ w0, const float* __restrict__ b0,
    const float* __restrict__ w1, const float* __restrict__ b1,
    const float* __restrict__ masks, float* __restrict__ ws){
  uint_t* P1H = (uint_t*)(ws + OFF_P1H);
  int t = blockIdx.x, j = threadIdx.x;
  __shared__ float xl[32*80];
  __shared__ float p0l[32*256];
  __shared__ float p1s[256*32];
  for (int i=j; i<32*80; i+=256){
    int b = i/80, o = i%80;
    xl[i] = (t==0) ? 0.f : tgt[((size_t)b*TD_ + (t-1))*80 + o];
  }
  __syncthreads();
  {
    float bj = b0[j];
    float w[80];
    #pragma unroll
    for (int o=0;o<80;o++) w[o] = w0[j*80+o];
    for (int b=0;b<32;b++){
      float a0=0,a1=0,a2=0,a3=0;
      const float* x = &xl[b*80];
      #pragma unroll
      for (int o=0;o<80;o+=4){
        a0+=w[o]*x[o]; a1+=w[o+1]*x[o+1]; a2+=w[o+2]*x[o+2]; a3+=w[o+3]*x[o+3];
      }
      float m = masks[(((size_t)t*2+0)*32+b)*256 + j];
      p0l[b*256 + j] = fmaxf(bj+a0+a1+a2+a3, 0.f) * m;
    }
  }
  __syncthreads();
  {
    float bj = b1[j];
    const float4* wr = (const float4*)(w1 + j*256);
    float acc[32];
    #pragma unroll
    for (int i=0;i<32;i++) acc[i]=0.f;
    for (int o4=0;o4<64;o4++){
      float4 w = wr[o4];
      #pragma unroll
      for (int b=0;b<32;b++){
        const float4 xv = *(const float4*)&p0l[b*256 + o4*4];
        acc[b] += w.x*xv.x + w.y*xv.y + w.z*xv.z + w.w*xv.w;
      }
    }
    for (int b=0;b<32;b++){
      float m = masks[(((size_t)t*2+1)*32+b)*256 + j];
      p1s[j*32 + b] = fmaxf(bj+acc[b], 0.f) * m;
    }
  }
  __syncthreads();
  for (int i=j; i<32*128; i+=256){
    int b = i >> 7, jp = i & 127;
    P1H[((size_t)t*32 + b)*128 + jp] = packh2(p1s[(2*jp)*32 + b], p1s[(2*jp+1)*32 + b]);
  }
}

// ---------------- per-step kernel A: attention(t) + outputs(t-2) ----------------

__global__ __launch_bounds__(512) void k_stepa(int t,
    const int* __restrict__ lens, const float* __restrict__ ww, const float* __restrict__ wb,
    const float* __restrict__ featw, const float* __restrict__ probw,
    const float* __restrict__ probb, float* __restrict__ ws, float* __restrict__ out){
  __shared__ __align__(16) uint_t h0l[512];
  __shared__ __align__(16) float Ml[128*32];
  __shared__ __align__(16) float apad[320];
  __shared__ __align__(16) float whl[128];
  __shared__ __align__(16) float wl[128];
  __shared__ __align__(16) float scl[256];
  __shared__ __align__(16) float awl[256];
  __shared__ __align__(16) float redl[128];
  __shared__ __align__(16) float psq[2048];
  __shared__ __align__(16) float redo[512];
  const int blk = blockIdx.x, tid = threadIdx.x;
  const int pc = t & 1, pp = pc ^ 1;
  uint_t* XC0 = (uint_t*)(ws + OFF_XC0);
  uint_t* XC1 = (uint_t*)(ws + OFF_XC1);
  float* ATTC = ws + OFF_ATTC;

  if (blk >= 32){
    // -------- output GEMV for step tt = t-2 --------
    if (t < 2) return;
    const int tt = t - 2;
    int ob = blk - 32;                 // 0..23
    int b = tid & 31, rr = (tid>>5)&3, ksq = tid>>7;
    int r = ob*4 + rr;                 // 0..95
    const float* wr = (r < 80) ? (featw + (size_t)r*1536) : probw;
    const float* acp = ATTC + (size_t)(tt%3)*16384 + b*512;
    float acc = 0.f;
    for (int j=0;j<96;j++){
      int k = ksq*384 + j*4;
      float x0,x1,x2,x3;
      if (k < 1024){
        uint2 hw = *(const uint2*)(XC1 + b*1024 + pc*512 + (k>>1));
        half2_t ha = __builtin_bit_cast(half2_t, hw.x);
        half2_t hb = __builtin_bit_cast(half2_t, hw.y);
        x0 = (float)ha[0]; x1 = (float)ha[1]; x2 = (float)hb[0]; x3 = (float)hb[1];
      } else {
        float4 f = *(const float4*)(acp + (k-1024));
        x0 = f.x; x1 = f.y; x2 = f.z; x3 = f.w;
      }
      if (r <= 80){
        float4 wv = *(const float4*)(wr + k);
        acc += wv.x*x0 + wv.y*x1 + wv.z*x2 + wv.w*x3;
      }
    }
    redo[(rr*4+ksq)*32 + b] = acc;
    __syncthreads();
    if (tid < 128){
      int b2 = tid&31, r2 = tid>>5;
      float vsum = redo[(r2*4+0)*32+b2] + redo[(r2*4+1)*32+b2]
                 + redo[(r2*4+2)*32+b2] + redo[(r2*4+3)*32+b2];
      int rr2 = ob*4 + r2;
      if (rr2 < 80)       out[((size_t)b2*80 + rr2)*256 + tt] = vsum;
      else if (rr2 == 80) out[LOG_OFF + (size_t)b2*256 + tt] = vsum + probb[0];
    }
    return;
  }

  // -------- attention for batch b = blk --------
  if (t >= TD_) return;
  const int b = blk;
  const int len = lens[b];
  const float* PM = ws + OFF_PM;
  const float* Mg = ws + OFF_M;
  const uint_t* WWHT = (const uint_t*)(ws + OFF_WWHT);
  const uint_t* ENCH = (const uint_t*)(ws + OFF_ENCH);
  const uint_t* P1H = (const uint_t*)(ws + OFF_P1H);
  float* CUM = ws + OFF_CUM;

  if (tid < 128)
    *(uint4*)(h0l + tid*4) = *(const uint4*)(XC0 + b*1408 + 384 + pp*512 + tid*4);
  for (int i=tid; i<128*31; i+=512) Ml[(i/31)*32 + (i%31)] = Mg[i];
  for (int i=tid; i<288; i+=512){
    int p = i - 15;
    float vv = 0.f;
    if (p >= 0 && p < 256)
      vv = (t==0) ? ((p < len) ? 1.0f/(float)len : 0.f) : CUM[b*256 + p];
    apad[i] = vv;
  }
  if (tid < 128) wl[tid] = ww[tid];
  __syncthreads();
  // ---- Wh = Ww . h0(t-1) via TRANSPOSED weights (coalesced along a) ----
  {
    int aW = tid & 127, qW = tid >> 7;      // 4 K-slices of 128 pairs
    const uint_t* wt = WWHT + (size_t)(qW*128)*128 + aW;
    const uint_t* hb = h0l + qW*128;
    float s0 = 0.f, s1 = 0.f;
    #pragma unroll 8
    for (int p=0;p<128;p+=2){
      s0 = dot2f(wt[(size_t)p*128],     hb[p],   s0);
      s1 = dot2f(wt[(size_t)(p+1)*128], hb[p+1], s1);
    }
    psq[qW*128 + aW] = s0 + s1;
  }
  __syncthreads();
  if (tid < 128) whl[tid] = psq[tid] + psq[128+tid] + psq[256+tid] + psq[384+tid];
  __syncthreads();
  // ---- scores ----
  {
    int pg = tid & 63, q = tid >> 6;
    float apw[36];
    #pragma unroll
    for (int i=0;i<36;i+=4) *(float4*)&apw[i] = *(const float4*)&apad[pg*4 + i];
    float part0=0, part1=0, part2=0, part3=0;
    const float* pmb = PM + (size_t)b*128*256;
    for (int aa=0; aa<16; aa++){
      int a = q*16 + aa;
      const float* mr = Ml + a*32;
      float4 pv = *(const float4*)(pmb + (size_t)a*256 + pg*4);
      float wa = whl[a];
      float u0 = pv.x + wa, u1 = pv.y + wa, u2 = pv.z + wa, u3 = pv.w + wa;
      #pragma unroll
      for (int k=0;k<28;k+=4){
        float4 m4 = *(const float4*)(mr + k);
        u0 += m4.x*apw[k]   + m4.y*apw[k+1] + m4.z*apw[k+2] + m4.w*apw[k+3];
        u1 += m4.x*apw[k+1] + m4.y*apw[k+2] + m4.z*apw[k+3] + m4.w*apw[k+4];
        u2 += m4.x*apw[k+2] + m4.y*apw[k+3] + m4.z*apw[k+4] + m4.w*apw[k+5];
        u3 += m4.x*apw[k+3] + m4.y*apw[k+4] + m4.z*apw[k+5] + m4.w*apw[k+6];
      }
      float m28 = mr[28], m29 = mr[29], m30 = mr[30];
      u0 += m28*apw[28] + m29*apw[29] + m30*apw[30];
      u1 += m28*apw[29] + m29*apw[30] + m30*apw[31];
      u2 += m28*apw[30] + m29*apw[31] + m30*apw[32];
      u3 += m28*apw[31] + m29*apw[32] + m30*apw[33];
      float wv = wl[a];
      part0 += tanh_f(u0)*wv; part1 += tanh_f(u1)*wv;
      part2 += tanh_f(u2)*wv; part3 += tanh_f(u3)*wv;
    }
    float4 pp2; pp2.x = part0; pp2.y = part1; pp2.z = part2; pp2.w = part3;
    *(float4*)&psq[tid*4] = pp2;
  }
  __syncthreads();
  if (tid < 256){
    float s = wb[0];
    int pgg = tid >> 2, d = tid & 3;
    #pragma unroll
    for (int qq=0;qq<8;qq++) s += psq[(qq*64 + pgg)*4 + d];
    scl[tid] = (tid >= len) ? -1.0e9f : s;
  }
  __syncthreads();
  if (tid < 128) redl[tid] = fmaxf(scl[tid], scl[tid+128]);
  __syncthreads();
  if (tid < 64){
    float v = fmaxf(redl[tid], redl[tid+64]);
    #pragma unroll
    for (int off=32; off>0; off>>=1) v = fmaxf(v, __shfl_down(v, off));
    if (tid==0) redl[0] = v;
  }
  __syncthreads();
  float mx = redl[0];
  if (tid < 256) awl[tid] = __expf(scl[tid]-mx);
  __syncthreads();
  if (tid < 128) redl[tid] = awl[tid] + awl[tid+128];
  __syncthreads();
  if (tid < 64){
    float v = redl[tid] + redl[tid+64];
    #pragma unroll
    for (int off=32; off>0; off>>=1) v += __shfl_down(v, off);
    if (tid==0) redl[0] = v;
  }
  __syncthreads();
  float inv = rcp_f(redl[0]);
  if (tid < 256){
    float aw = awl[tid]*inv;
    awl[tid] = aw;
    CUM[b*256 + tid] += aw;
    out[ATTW_OFF + ((size_t)b*TD_ + t)*256 + tid] = aw;
  }
  __syncthreads();
  // ---- context (fp16 enc) ----
  {
    int el = tid & 127, ph = tid >> 7;
    const uint_t* ep = ENCH + ((size_t)b*256 + ph*64)*256 + el*2;
    float c0=0,c1=0,c2=0,c3=0;
    for (int p=0;p<64;p++){
      float a = awl[ph*64 + p];
      uint2 ev = *(const uint2*)(ep + (size_t)p*256);
      half2_t h0v = __builtin_bit_cast(half2_t, ev.x);
      half2_t h1v = __builtin_bit_cast(half2_t, ev.y);
      c0 += a*(float)h0v[0]; c1 += a*(float)h0v[1];
      c2 += a*(float)h1v[0]; c3 += a*(float)h1v[1];
    }
    float4 ca; ca.x=c0; ca.y=c1; ca.z=c2; ca.w=c3;
    *(float4*)&psq[(ph*128 + el)*4] = ca;
  }
  __syncthreads();
  if (tid < 128){
    float4 s = *(const float4*)&psq[tid*4];
    #pragma unroll
    for (int g=1; g<4; g++){
      float4 o = *(const float4*)&psq[(g*128+tid)*4];
      s.x+=o.x; s.y+=o.y; s.z+=o.z; s.w+=o.w;
    }
    *(float4*)(ATTC + (size_t)(t%3)*16384 + b*512 + tid*4) = s;
    XC0[b*1408 + tid*2]     = packh2(s.x, s.y);
    XC0[b*1408 + tid*2 + 1] = packh2(s.z, s.w);
    XC0[b*1408 + 256 + tid] = P1H[((size_t)t*32 + b)*128 + tid];
  }
}

// ---------------- per-step kernel B: lstm0(t) [blk<256] + lstm1(t-1) [blk>=256] ----------------
// 4 units/block, 16 gate-rows in LDS (fp16 pairs, padded stride), x in 128-pair
// chunks with register prefetch. ~74.5KB LDS -> 2 blocks/CU.

__global__ __launch_bounds__(512) void k_stepb(int t,
    const float* __restrict__ l0bih, const float* __restrict__ l0bhh,
    const float* __restrict__ l1bih, const float* __restrict__ l1bhh,
    float* __restrict__ ws){
  __shared__ __align__(16) uint_t lds[16*1028 + 32*132];   // 16448 + 4224 = 20672 uints (80.7KB)
  uint_t* wlds = lds;
  uint_t* xl   = lds + 16*1028;
  float*  gs   = (float*)lds;          // alias over weights after compute done
  const int tid = threadIdx.x;
  const int pc = t & 1, pp = pc ^ 1;
  const int bp = tid & 15, ul = (tid>>4)&3, kq = tid>>6;   // kq 0..7
  const int sb = tid >> 4, sp = (tid & 15) * 8;            // staging: batch, pair-offset
  const bool is0 = blockIdx.x < 256;
  const int u0 = (is0 ? blockIdx.x : blockIdx.x - 256) * 4;
  uint_t* XC0 = (uint_t*)(ws + OFF_XC0);
  uint_t* XC1 = (uint_t*)(ws + OFF_XC1);
  _Float16* XC0h = (_Float16*)XC0;
  _Float16* XC1h = (_Float16*)XC1;

  if (is0){
    if (t >= TD_) return;
    const uint_t* W0P = (const uint_t*)(ws + OFF_W0P);
    // stage weights: 16 rows x 896 pairs -> stride 904
    for (int i=tid; i<16*896; i+=512){
      int r = i/896, p = i - r*896;
      wlds[r*904 + p] = W0P[(size_t)((r&3)*1024 + u0 + (r>>2))*896 + p];
    }
    float a0[4]={0,0,0,0}, a1[4]={0,0,0,0};
    uint4 rx0, rx1;
    { const uint_t* src = XC0 + sb*1408 + sp;
      rx0 = *(const uint4*)src; rx1 = *(const uint4*)(src+4); }
    #pragma unroll 1
    for (int c=0;c<7;c++){
      __syncthreads();
      *(uint4*)(xl + sb*132 + sp)     = rx0;
      *(uint4*)(xl + sb*132 + sp + 4) = rx1;
      __syncthreads();
      if (c+1 < 7){
        int co = (c+1)*128 + sp;
        const uint_t* src = (co < 384) ? (XC0 + sb*1408 + co)
                                       : (XC0 + sb*1408 + 384 + pp*512 + (co-384));
        rx0 = *(const uint4*)src; rx1 = *(const uint4*)(src+4);
      }
      const int wb = c*128 + kq*16;
      const uint_t* xpa = xl + bp*132 + kq*16;
      const uint_t* xpb = xl + (bp+16)*132 + kq*16;
      uint2 xa[8], xb[8];
      #pragma unroll
      for (int j=0;j<8;j++){ xa[j] = *(const uint2*)(xpa + 2*j); xb[j] = *(const uint2*)(xpb + 2*j); }
      #pragma unroll
      for (int g=0; g<4; g++){
        const uint_t* wr = wlds + (g + 4*ul)*904 + wb;
        float s0 = a0[g], s1 = a1[g];
        #pragma unroll
        for (int j=0;j<8;j++){
          uint2 w = *(const uint2*)(wr + 2*j);
          s0 = dot2f(w.x, xa[j].x, s0); s0 = dot2f(w.y, xa[j].y, s0);
          s1 = dot2f(w.x, xb[j].x, s1); s1 = dot2f(w.y, xb[j].y, s1);
        }
        a0[g] = s0; a1[g] = s1;
      }
    }
    __syncthreads();
    #pragma unroll
    for (int g=0; g<4; g++){
      gs[(kq*16 + g + 4*ul)*33 + bp]      = a0[g];
      gs[(kq*16 + g + 4*ul)*33 + bp + 16] = a1[g];
    }
    __syncthreads();
    if (tid < 128){
      int b = tid & 31, uu = tid >> 5;
      int u = u0 + uu;
      float g4[4];
      #pragma unroll
      for (int g=0; g<4; g++){
        float s = 0.f;
        #pragma unroll
        for (int k2=0;k2<8;k2++) s += gs[(k2*16 + g + 4*uu)*33 + b];
        g4[g] = s + l0bih[g*1024+u] + l0bhh[g*1024+u];
      }
      float c_old = (ws + OFF_C0)[u*32 + b];
      float h_old = (float)XC0h[b*2816 + 768 + pp*1024 + u];
      float cn = sigm(g4[1])*c_old + sigm(g4[0])*tanh_f(g4[2]);
      float hn = sigm(g4[3])*tanh_f(cn);
      (ws + OFF_C0)[u*32 + b] = 0.1f*c_old + 0.9f*cn;
      XC0h[b*2816 + 768 + pc*1024 + u] = (_Float16)(0.1f*h_old + 0.9f*hn);
    }
  } else {
    if (t < 1) return;
    const uint_t* W1P = (const uint_t*)(ws + OFF_W1P);
    for (int i=tid; i<16*1024; i+=512){
      int r = i >> 10, p = i & 1023;
      wlds[r*1028 + p] = W1P[(size_t)((r&3)*1024 + u0 + (r>>2))*1024 + p];
    }
    float a0[4]={0,0,0,0}, a1[4]={0,0,0,0};
    uint4 rx0, rx1;
    { const uint_t* src = XC0 + sb*1408 + 384 + pp*512 + sp;
      rx0 = *(const uint4*)src; rx1 = *(const uint4*)(src+4); }
    #pragma unroll 1
    for (int c=0;c<8;c++){
      __syncthreads();
      *(uint4*)(xl + sb*132 + sp)     = rx0;
      *(uint4*)(xl + sb*132 + sp + 4) = rx1;
      __syncthreads();
      if (c+1 < 8){
        int co = (c+1)*128 + sp;
        const uint_t* src = (co < 512) ? (XC0 + sb*1408 + 384 + pp*512 + co)
                                       : (XC1 + sb*1024 + pc*512 + (co-512));
        rx0 = *(const uint4*)src; rx1 = *(const uint4*)(src+4);
      }
      const int wb = c*128 + kq*16;
      const uint_t* xpa = xl + bp*132 + kq*16;
      const uint_t* xpb = xl + (bp+16)*132 + kq*16;
      uint2 xa[8], xb[8];
      #pragma unroll
      for (int j=0;j<8;j++){ xa[j] = *(const uint2*)(xpa + 2*j); xb[j] = *(const uint2*)(xpb + 2*j); }
      #pragma unroll
      for (int g=0; g<4; g++){
        const uint_t* wr = wlds + (g + 4*ul)*1028 + wb;
        float s0 = a0[g], s1 = a1[g];
        #pragma unroll
        for (int j=0;j<8;j++){
          uint2 w = *(const uint2*)(wr + 2*j);
          s0 = dot2f(w.x, xa[j].x, s0); s0 = dot2f(w.y, xa[j].y, s0);
          s1 = dot2f(w.x, xb[j].x, s1); s1 = dot2f(w.y, xb[j].y, s1);
        }
        a0[g] = s0; a1[g] = s1;
      }
    }
    __syncthreads();
    #pragma unroll
    for (int g=0; g<4; g++){
      gs[(kq*16 + g + 4*ul)*33 + bp]      = a0[g];
      gs[(kq*16 + g + 4*ul)*33 + bp + 16] = a1[g];
    }
    __syncthreads();
    if (tid < 128){
      int b = tid & 31, uu = tid >> 5;
      int u = u0 + uu;
      float g4[4];
      #pragma unroll
      for (int g=0; g<4; g++){
        float s = 0.f;
        #pragma unroll
        for (int k2=0;k2<8;k2++) s += gs[(k2*16 + g + 4*uu)*33 + b];
        g4[g] = s + l1bih[g*1024+u] + l1bhh[g*1024+u];
      }
      float c_old = (ws + OFF_C1)[u*32 + b];
      float h_old = (float)XC1h[b*2048 + pc*1024 + u];   // h1(t-2)
      float cn = sigm(g4[1])*c_old + sigm(g4[0])*tanh_f(g4[2]);
      float hn = sigm(g4[3])*tanh_f(cn);
      (ws + OFF_C1)[u*32 + b] = 0.1f*c_old + 0.9f*cn;
      XC1h[b*2048 + pp*1024 + u] = (_Float16)(0.1f*h_old + 0.9f*hn);  // h1(t-1)
    }
  }
}

extern "C" void kernel_launch(void* const* d_in, const int* in_sizes, int n_in,
                              void* d_out, int out_size, void* d_ws, size_t ws_size,
                              hipStream_t stream){
  const float* enc   = (const float*)d_in[0];
  const float* tgt   = (const float*)d_in[1];
  const float* masks = (const float*)d_in[2];
  const int*   lens  = (const int*)  d_in[3];
  const float* Vw    = (const float*)d_in[4];
  const float* Vb    = (const float*)d_in[5];
  const float* Ww    = (const float*)d_in[6];
  const float* Uw    = (const float*)d_in[7];
  const float* Fw    = (const float*)d_in[8];
  const float* ww    = (const float*)d_in[9];
  const float* wb    = (const float*)d_in[10];
  const float* pw0   = (const float*)d_in[11];
  const float* pb0   = (const float*)d_in[12];
  const float* pw1   = (const float*)d_in[13];
  const float* pb1   = (const float*)d_in[14];
  const float* l0wih = (const float*)d_in[15];
  const float* l0whh = (const float*)d_in[16];
  const float* l0bih = (const float*)d_in[17];
  const float* l0bhh = (const float*)d_in[18];
  const float* l1wih = (const float*)d_in[19];
  const float* l1whh = (const float*)d_in[20];
  const float* l1bih = (const float*)d_in[21];
  const float* l1bhh = (const float*)d_in[22];
  const float* featw = (const float*)d_in[23];
  const float* probw = (const float*)d_in[24];
  const float* probb = (const float*)d_in[25];
  float* ws  = (float*)d_ws;
  float* out = (float*)d_out;

  k_init   <<<256, 256,0,stream>>>(ws);
  k_pre    <<<256, 256,0,stream>>>(tgt, pw0, pb0, pw1, pb1, masks, ws);
  k_precm  <<<1,   256,0,stream>>>(Uw, Fw, ws);
  k_cvtww  <<<512, 128,0,stream>>>(Ww, ws);
  k_packenc<<<8192,256,0,stream>>>(enc, ws);
  k_packw0 <<<4096,256,0,stream>>>(l0wih, l0whh, ws);
  k_packw1 <<<4096,256,0,stream>>>(l1wih, l1whh, ws);
  k_pm     <<<128, 256,0,stream>>>(enc, Vw, Vb, ws);

  for (int t = 0; t < TD_; t++){
    k_stepa<<<56, 512,0,stream>>>(t, lens, ww, wb, featw, probw, probb, ws, out);
    k_stepb<<<512,512,0,stream>>>(t, l0bih, l0bhh, l1bih, l1bhh, ws);
  }
  k_stepb<<<512,512,0,stream>>>(256, l0bih, l0bhh, l1bih, l1bhh, ws);              // lstm1(255)
  k_stepa<<<56, 512,0,stream>>>(256, lens, ww, wb, featw, probw, probb, ws, out);  // out(254)
  k_stepa<<<56, 512,0,stream>>>(257, lens, ww, wb, featw, probw, probb, ws, out);  // out(255)
}